// Round 1
// baseline (984.893 us; speedup 1.0000x reference)
//
#include <hip/hip_runtime.h>

typedef unsigned short u16;
typedef unsigned int   u32;
typedef __attribute__((ext_vector_type(8))) __bf16 bf16x8;
typedef __attribute__((ext_vector_type(4))) float  f32x4;

__device__ __forceinline__ float bf2f(u16 u) {
    union { u32 i; float f; } v; v.i = ((u32)u) << 16; return v.f;
}
__device__ __forceinline__ u16 f2bf(float f) {
    u32 u = __float_as_uint(f);
    u32 r = (u + 0x7FFFu + ((u >> 16) & 1u)) >> 16;
    return (u16)r;
}

// ---------------------------------------------------------------------------
// Kernel 1: grouped directional conv 5x5, C=32 -> 256, pad=2, no bias.
// x: NCHW f32 (8,32,128,128); out coeffs: NHWC bf16 (8,128,128,256).
// block = (n, y, cc) cc = chunk of 8 input channels (64 output chans).
// ---------------------------------------------------------------------------
__global__ __launch_bounds__(256) void dir_conv_k(const float* __restrict__ x,
                                                  const float* __restrict__ wd,
                                                  u16* __restrict__ coeffs) {
    int bid = blockIdx.x;
    int cc = bid & 3, y = (bid >> 2) & 127, n = bid >> 9;
    __shared__ float lx[5280];   // [8 c][5 ky][132 xx] (2-col zero pad each side)
    __shared__ float lw[1600];   // [25 tap][64 oc_local]
    int t = threadIdx.x;
    for (int i = t; i < 1600; i += 256) {
        int ol = i / 25, tap = i - ol * 25;
        lw[tap * 64 + ol] = wd[(cc * 64 + ol) * 25 + tap];
    }
    for (int i = t; i < 5280; i += 256) {
        int c = i / 660, rem = i - c * 660;
        int ky = rem / 132, xx = rem - ky * 132;
        int gy = y - 2 + ky, gx = xx - 2;
        float v = 0.f;
        if (gy >= 0 && gy < 128 && gx >= 0 && gx < 128)
            v = x[(((n * 32 + cc * 8 + c) * 128 + gy) << 7) + gx];
        lx[i] = v;
    }
    __syncthreads();
    int px = t >> 1, oh = t & 1;   // pixel x, oc-half (32 ocs each)
    float acc[4][8];
#pragma unroll
    for (int j = 0; j < 4; ++j)
#pragma unroll
        for (int d = 0; d < 8; ++d) acc[j][d] = 0.f;

#pragma unroll
    for (int j = 0; j < 4; ++j) {
        int cl = oh * 4 + j;                       // input channel 0..7 in chunk
        const float* lxc = &lx[cl * 660];
#pragma unroll
        for (int ky = 0; ky < 5; ++ky)
#pragma unroll
            for (int kx = 0; kx < 5; ++kx) {
                float xv = lxc[ky * 132 + px + kx];
                const float* w8 = &lw[(ky * 5 + kx) * 64 + cl * 8];
#pragma unroll
                for (int d = 0; d < 8; ++d) acc[j][d] += xv * w8[d];
            }
    }
    long base = ((long)((n * 128 + y) * 128 + px)) * 256 + cc * 64 + oh * 32;
#pragma unroll
    for (int j = 0; j < 4; ++j) {
        uint4 o;
        o.x = (u32)f2bf(acc[j][0]) | ((u32)f2bf(acc[j][1]) << 16);
        o.y = (u32)f2bf(acc[j][2]) | ((u32)f2bf(acc[j][3]) << 16);
        o.z = (u32)f2bf(acc[j][4]) | ((u32)f2bf(acc[j][5]) << 16);
        o.w = (u32)f2bf(acc[j][6]) | ((u32)f2bf(acc[j][7]) << 16);
        *(uint4*)(coeffs + base + j * 8) = o;
    }
}

// ---------------------------------------------------------------------------
// Repack conv weights OIHW f32 -> MFMA-B-fragment-order bf16:
// wp[((tap*KC + kc)*OC + oc)*32 + khalf*8 + j] = w[oc][kc*32+khalf*8+j][tap]
// ---------------------------------------------------------------------------
__global__ __launch_bounds__(256) void repack_w_k(const float* __restrict__ w,
                                                  u16* __restrict__ wp,
                                                  int OC, int IC, int total) {
    int f = blockIdx.x * 256 + threadIdx.x;
    if (f >= total) return;
    int KC = IC >> 5;
    int j  = f & 7;
    int kh = (f >> 3) & 3;
    int g  = f >> 5;           // (tap*KC + kc)*OC + oc
    int oc = g % OC;
    int r  = g / OC;
    int kc = r % KC;
    int tap = r / KC;
    int ic = kc * 32 + kh * 8 + j;
    wp[f] = f2bf(w[(oc * IC + ic) * 9 + tap]);
}

// ---------------------------------------------------------------------------
// 3x3 conv, NHWC bf16 in/out, implicit GEMM with mfma_f32_16x16x32_bf16.
// Block tile: 64 pixels (one row segment) x 128 ocs; 4 waves x (64px x 32oc).
// K loop: 32-ic chunks x 9 taps. A staged in LDS [3][66][32], B from global
// (fragment-packed, L2-resident). Adds bias, writes bf16.
// ---------------------------------------------------------------------------
template<int IC, int OC>
__global__ __launch_bounds__(256) void conv3_k(const u16* __restrict__ in,
                                               const u16* __restrict__ wp,
                                               const float* __restrict__ bias,
                                               u16* __restrict__ outp) {
    constexpr int KC = IC / 32;
    int bx = blockIdx.x;
    int xh = bx & 1, y = (bx >> 1) & 127, n = bx >> 8;
    int ocb = blockIdx.y;
    int t = threadIdx.x, lane = t & 63, wv = t >> 6;
    int x0 = xh << 6;
    int row_m = lane & 15, khf = lane >> 4;
    __shared__ uint4 lA[792];                    // [3][66][32] bf16 = 12672 B
    const u16* lAu = (const u16*)lA;
    f32x4 acc[4][2];
    f32x4 zero = {0.f, 0.f, 0.f, 0.f};
#pragma unroll
    for (int mf = 0; mf < 4; ++mf) { acc[mf][0] = zero; acc[mf][1] = zero; }

    for (int kc = 0; kc < KC; ++kc) {
        for (int i = t; i < 792; i += 256) {     // stage A tile (16B chunks)
            int seg = i >> 2, part = i & 3;
            int ih = seg / 66, ix = seg - ih * 66;
            int yy = y - 1 + ih, xx = x0 - 1 + ix;
            uint4 v = make_uint4(0, 0, 0, 0);
            if (yy >= 0 && yy < 128 && xx >= 0 && xx < 128) {
                const u16* src = in + ((long)((n * 128 + yy) * 128 + xx)) * IC
                                 + kc * 32 + part * 8;
                v = *(const uint4*)src;
            }
            lA[i] = v;
        }
        __syncthreads();
#pragma unroll
        for (int dy = 0; dy < 3; ++dy) {
#pragma unroll
            for (int dx = 0; dx < 3; ++dx) {
                int tap = dy * 3 + dx;
                long wbase = ((long)(tap * KC + kc) * OC
                              + (ocb * 128 + wv * 32 + row_m)) * 32 + khf * 8;
                bf16x8 b0 = *(const bf16x8*)(wp + wbase);
                bf16x8 b1 = *(const bf16x8*)(wp + wbase + 512);  // oc+16
                int abase = (dy * 66 + dx + row_m) * 32 + khf * 8;
#pragma unroll
                for (int mf = 0; mf < 4; ++mf) {
                    bf16x8 a = *(const bf16x8*)(lAu + abase + mf * 512);
                    acc[mf][0] = __builtin_amdgcn_mfma_f32_16x16x32_bf16(a, b0, acc[mf][0], 0, 0, 0);
                    acc[mf][1] = __builtin_amdgcn_mfma_f32_16x16x32_bf16(a, b1, acc[mf][1], 0, 0, 0);
                }
            }
        }
        __syncthreads();
    }
    int oc0 = ocb * 128 + wv * 32 + row_m;
    float bia0 = bias[oc0], bia1 = bias[oc0 + 16];
    long rb = ((long)((n * 128 + y) * 128)) * OC;
#pragma unroll
    for (int mf = 0; mf < 4; ++mf)
#pragma unroll
        for (int r = 0; r < 4; ++r) {
            int p = x0 + mf * 16 + khf * 4 + r;
            long ob = rb + (long)p * OC;
            outp[ob + oc0]      = f2bf(acc[mf][0][r] + bia0);
            outp[ob + oc0 + 16] = f2bf(acc[mf][1][r] + bia1);
        }
}

// ---------------------------------------------------------------------------
// BN stats, stage 1: per-block partial (sum, sumsq) per channel over 1024 rows.
// ---------------------------------------------------------------------------
template<int C>
__global__ __launch_bounds__(256) void stats1_k(const u16* __restrict__ h,
                                                float* __restrict__ part) {
    constexpr int CH2 = C / 2;
    constexpr int PARTS = 256 / CH2;
    constexpr int RPB = 1024;
    constexpr int RPT = RPB / PARTS;
    int t = threadIdx.x;
    int chp = t % CH2, rp = t / CH2;
    long row0 = (long)blockIdx.x * RPB + (long)rp * RPT;
    float s0 = 0.f, q0 = 0.f, s1 = 0.f, q1 = 0.f;
    const u16* base = h + row0 * C + chp * 2;
    for (int r = 0; r < RPT; ++r) {
        u32 v = *(const u32*)(base + (long)r * C);
        float a = bf2f((u16)(v & 0xffff));
        float b = bf2f((u16)(v >> 16));
        s0 += a; q0 += a * a; s1 += b; q1 += b * b;
    }
    float4 o = make_float4(s0, q0, s1, q1);
    *(float4*)(part + ((long)(blockIdx.x * PARTS + rp) * CH2 + chp) * 4) = o;
}

// Stage 2: reduce partials -> per-channel affine (a, b): a*x+b == BN(x)
template<int C>
__global__ __launch_bounds__(256) void stats2_k(const float* __restrict__ part,
                                                const float* __restrict__ g,
                                                const float* __restrict__ be,
                                                float* __restrict__ ab) {
    constexpr int CH2 = C / 2;
    constexpr int NP = 128 * (256 / CH2);
    int ch = blockIdx.x * 256 + threadIdx.x;
    if (ch >= C) return;
    int chp = ch >> 1, lo = ch & 1;
    float s = 0.f, q = 0.f;
    for (int p = 0; p < NP; ++p) {
        s += part[((long)p * CH2 + chp) * 4 + lo * 2];
        q += part[((long)p * CH2 + chp) * 4 + lo * 2 + 1];
    }
    const float M = 131072.f;
    float mean = s / M;
    float var = q / M - mean * mean;
    float a = g[ch] * rsqrtf(var + 1e-5f);
    ab[ch * 2]     = a;
    ab[ch * 2 + 1] = be[ch] - mean * a;
}

// ---------------------------------------------------------------------------
// BN1 + ReLU in place on h1 (NHWC bf16, C=512). 8 elems/thread.
// ---------------------------------------------------------------------------
__global__ __launch_bounds__(256) void bn_relu_k(u16* __restrict__ h,
                                                 const float* __restrict__ ab) {
    long idx8 = (long)blockIdx.x * 256 + threadIdx.x;
    u16* p = h + idx8 * 8;
    uint4 v = *(const uint4*)p;
    int chb = ((int)idx8 & 63) << 3;
    u32 w[4] = {v.x, v.y, v.z, v.w};
    u32 o[4];
#pragma unroll
    for (int q = 0; q < 4; ++q) {
        int ch = chb + q * 2;
        float2 a0 = *(const float2*)(ab + ch * 2);
        float2 a1 = *(const float2*)(ab + ch * 2 + 2);
        float f0 = bf2f((u16)(w[q] & 0xffff));
        float f1 = bf2f((u16)(w[q] >> 16));
        f0 = fmaxf(f0 * a0.x + a0.y, 0.f);
        f1 = fmaxf(f1 * a1.x + a1.y, 0.f);
        o[q] = (u32)f2bf(f0) | ((u32)f2bf(f1) << 16);
    }
    *(uint4*)p = make_uint4(o[0], o[1], o[2], o[3]);
}

// ---------------------------------------------------------------------------
// Fused BN2+ReLU + 1x1 inverse conv (256 -> 32) + bias. Writes NCHW f32 out.
// One thread per pixel, acc over 32 ocs; w_inv transposed into LDS [k][oc].
// ---------------------------------------------------------------------------
__global__ __launch_bounds__(256) void inv_conv_k(const u16* __restrict__ h2,
                                                  const float* __restrict__ ab,
                                                  const float* __restrict__ winv,
                                                  const float* __restrict__ binv,
                                                  float* __restrict__ out) {
    __shared__ float lw[8192];   // [256 k][32 oc]
    __shared__ float lab[512];
    int t = threadIdx.x;
    for (int i = t; i < 8192; i += 256) {
        int k = i >> 5, oc = i & 31;
        lw[i] = winv[oc * 256 + k];
    }
    lab[t] = ab[t];
    lab[t + 256] = ab[t + 256];
    __syncthreads();
    long p = (long)blockIdx.x * 256 + t;
    const u16* hp = h2 + p * 256;
    f32x4 acc[8];
    f32x4 zero = {0.f, 0.f, 0.f, 0.f};
#pragma unroll
    for (int q = 0; q < 8; ++q) acc[q] = zero;
    for (int k = 0; k < 256; k += 8) {
        uint4 hv = *(const uint4*)(hp + k);
        u32 wv[4] = {hv.x, hv.y, hv.z, hv.w};
#pragma unroll
        for (int e = 0; e < 8; ++e) {
            u16 us = (e & 1) ? (u16)(wv[e >> 1] >> 16) : (u16)(wv[e >> 1] & 0xffff);
            int kk = k + e;
            float v = bf2f(us);
            v = fmaxf(v * lab[kk * 2] + lab[kk * 2 + 1], 0.f);
            const f32x4* w4 = (const f32x4*)(lw + kk * 32);
#pragma unroll
            for (int q = 0; q < 8; ++q) acc[q] += v * w4[q];
        }
    }
    int n = (int)(p >> 14), rem = (int)(p & 16383);
#pragma unroll
    for (int q = 0; q < 8; ++q)
#pragma unroll
        for (int c = 0; c < 4; ++c) {
            int oc = q * 4 + c;
            out[((long)(n * 32 + oc) << 14) + rem] = acc[q][c] + binv[oc];
        }
}

// ---------------------------------------------------------------------------
// Workspace layout (bytes):
//   0         w1p   (2,359,296)
//   2359296   w2p   (2,359,296)
//   4718592   part  (524,288)
//   5242880   ab1   (4,096)
//   5246976   ab2   (2,048)
//   8388608   coeffs / h2 (67,108,864)   -- coeffs dead after conv1, reused
//   75497472  h1    (134,217,728)        -- BN1 applied in place
// total ~200 MB
// ---------------------------------------------------------------------------
extern "C" void kernel_launch(void* const* d_in, const int* in_sizes, int n_in,
                              void* d_out, int out_size, void* d_ws, size_t ws_size,
                              hipStream_t stream) {
    const float* x     = (const float*)d_in[0];
    const float* w_dir = (const float*)d_in[1];
    const float* w1    = (const float*)d_in[2];
    const float* b1    = (const float*)d_in[3];
    const float* g1    = (const float*)d_in[4];
    const float* be1   = (const float*)d_in[5];
    const float* w2    = (const float*)d_in[6];
    const float* b2    = (const float*)d_in[7];
    const float* g2    = (const float*)d_in[8];
    const float* be2   = (const float*)d_in[9];
    const float* w_inv = (const float*)d_in[10];
    const float* b_inv = (const float*)d_in[11];
    float* out = (float*)d_out;
    char* ws = (char*)d_ws;

    u16*   w1p  = (u16*)(ws + 0);
    u16*   w2p  = (u16*)(ws + 2359296);
    float* part = (float*)(ws + 4718592);
    float* ab1  = (float*)(ws + 5242880);
    float* ab2  = (float*)(ws + 5246976);
    u16*   coef = (u16*)(ws + 8388608);     // also h2
    u16*   h1   = (u16*)(ws + 75497472);

    repack_w_k<<<4608, 256, 0, stream>>>(w1, w1p, 512, 256, 1179648);
    repack_w_k<<<4608, 256, 0, stream>>>(w2, w2p, 256, 512, 1179648);
    dir_conv_k<<<4096, 256, 0, stream>>>(x, w_dir, coef);
    conv3_k<256, 512><<<dim3(2048, 4), 256, 0, stream>>>(coef, w1p, b1, h1);
    stats1_k<512><<<128, 256, 0, stream>>>(h1, part);
    stats2_k<512><<<2, 256, 0, stream>>>(part, g1, be1, ab1);
    bn_relu_k<<<32768, 256, 0, stream>>>(h1, ab1);
    conv3_k<512, 256><<<dim3(2048, 2), 256, 0, stream>>>(h1, w2p, b2, coef);
    stats1_k<256><<<128, 256, 0, stream>>>(coef, part);
    stats2_k<256><<<1, 256, 0, stream>>>(part, g2, be2, ab2);
    inv_conv_k<<<512, 256, 0, stream>>>(coef, ab2, w_inv, b_inv, out);
}